// Round 20
// baseline (197.047 us; speedup 1.0000x reference)
//
#include <hip/hip_runtime.h>
#include <stdint.h>

#define S_LEN 2048
#define NHEAD 16
#define HDIM  64
#define HIDDEN 1024
#define BATCH 4

typedef float f32x4 __attribute__((ext_vector_type(4)));
typedef __bf16 bf16x8 __attribute__((ext_vector_type(8)));
typedef unsigned short u16;

union U4B8 { uint4 u; bf16x8 b; };

__device__ __forceinline__ bf16x8 as_b8(uint4 u){ U4B8 x; x.u = u; return x.b; }

__device__ __forceinline__ f32x4 mfma16(uint4 a, uint4 b, f32x4 c){
  return __builtin_amdgcn_mfma_f32_16x16x32_bf16(as_b8(a), as_b8(b), c, 0, 0, 0);
}

__device__ __forceinline__ u16 f2bf(float f){
  __bf16 h = (__bf16)f;
  return __builtin_bit_cast(u16, h);
}

__device__ __forceinline__ float exp2fast(float x){
  return __builtin_exp2f(x);            // v_exp_f32 (hardware is base-2)
}

__device__ __forceinline__ void gload16(const void* g, void* l){
  __builtin_amdgcn_global_load_lds(
      (const __attribute__((address_space(1))) unsigned int*)g,
      (__attribute__((address_space(3))) unsigned int*)l, 16, 0, 0);
}

#define QSCALE 0.18033688f   /* 0.125 * log2(e) */
#define DEFER_THR 11.5f      /* = 8 in ln-domain */

#define FENCE asm volatile("" ::: "memory")
#define PH_BAR do{ FENCE; __builtin_amdgcn_s_barrier(); FENCE; }while(0)

// ---------------- convert x: f32 -> bf16 ----------------
__global__ __launch_bounds__(256) void k_cvt(const float* __restrict__ in,
                                             u16* __restrict__ out, int n4){
  int i = blockIdx.x * 256 + threadIdx.x;
  int stride = gridDim.x * 256;
  for (; i < n4; i += stride){
    float4 v = ((const float4*)in)[i];
    unsigned lo = (unsigned)f2bf(v.x) | ((unsigned)f2bf(v.y) << 16);
    unsigned hi = (unsigned)f2bf(v.z) | ((unsigned)f2bf(v.w) << 16);
    ((uint2*)out)[i] = make_uint2(lo, hi);
  }
}

// ---------------- transpose+convert: f32 [K][N] -> bf16 [N][K] ----------------
__global__ __launch_bounds__(256) void k_transpose(const float* __restrict__ in,
                                                   u16* __restrict__ out,
                                                   int K, int N){
  __shared__ float t[32][33];
  int tx = threadIdx.x & 31, ty = threadIdx.x >> 5;
  int n0 = blockIdx.x * 32, k0 = blockIdx.y * 32;
  #pragma unroll
  for (int i = 0; i < 4; ++i)
    t[ty + i*8][tx] = in[(size_t)(k0 + ty + i*8) * N + n0 + tx];
  __syncthreads();
  #pragma unroll
  for (int i = 0; i < 4; ++i)
    out[(size_t)(n0 + ty + i*8) * K + k0 + tx] = f2bf(t[tx][ty + i*8]);
}

// ---- stage one 128x32 A-tile + 128x32 B-tile into LDS (4 loads/thread) ------
__device__ __forceinline__ void stage_gemm(
    const u16* __restrict__ A, const u16* __restrict__ Bt,
    u16* As, u16* Bs, int row0, int col0, int K, int k0, int wave, int lane)
{
  #pragma unroll
  for (int p = 0; p < 2; ++p){
    int chunk = wave * 128 + p * 64 + lane;   // 0..511
    int r = chunk >> 2, cseg = chunk & 3;
    int sseg = cseg ^ (r & 3);                // pre-swizzled source chunk
    const u16* ga = A  + (size_t)(row0 + r) * K + k0 + sseg * 8;
    gload16(ga, As + (size_t)(wave * 128 + p * 64) * 8);
    const u16* gb = Bt + (size_t)(col0 + r) * K + k0 + sseg * 8;
    gload16(gb, Bs + (size_t)(wave * 128 + p * 64) * 8);
  }
}

// ---------------- GEMM: C[M,N] = A[M,K](bf16) @ Bt[N,K](bf16)^T + bias -------
// 128x128 tile, 4 waves, BK=32. FOUR-slot LDS ring, depth-2 prefetch,
// counted vmcnt(8), SINGLE barrier per K-step (slot-lifetime proof: in
// segment ks the read slot is ks%4, staging targets (ks+3)%4, landing writes
// target (ks+2)%4 -- all distinct mod 4, and lagging waves' iter ks-1 reads
// completed before they arrived at BAR(ks)). T1 XCD row-band grid swizzle.
// MODE 0: scatter q (pre-scaled) / k into [B*H][S][D], V^T into [B*H][D][S].
// MODE 1: f32 out [M,N].
template<int MODE>
__global__ __launch_bounds__(256) void k_gemm(
    const u16* __restrict__ A, const u16* __restrict__ Bt,
    const float* __restrict__ bias,
    u16* __restrict__ oq, u16* __restrict__ ok, u16* __restrict__ ov,
    float* __restrict__ of, int M, int N, int K, int nx)
{
  __shared__ u16 As[4][128 * 32];   // 32 KB
  __shared__ u16 Bs[4][128 * 32];   // 32 KB
  const int tid  = threadIdx.x;
  const int wave = tid >> 6, lane = tid & 63;
  const int l4 = lane >> 4, lm = lane & 15;
  const int wr = wave >> 1, wc = wave & 1;

  // XCD row-band swizzle: xcd gets rows [xcd*ny/8, ...), all cols.
  const int bid = blockIdx.x;
  const int nwg = gridDim.x;
  const int ny8 = nwg / (8 * nx);           // row-panels per XCD
  const int xcd = bid & 7, t = bid >> 3;
  const int by = xcd * ny8 + t / nx;
  const int bx = t % nx;
  const int row0 = by * 128;
  const int col0 = bx * 128;

  const f32x4 fzero = {0.f, 0.f, 0.f, 0.f};
  f32x4 acc[4][4];
  #pragma unroll
  for (int m = 0; m < 4; ++m)
    #pragma unroll
    for (int n = 0; n < 4; ++n) acc[m][n] = fzero;

  const int nks = K >> 5;
  stage_gemm(A, Bt, &As[0][0], &Bs[0][0], row0, col0, K, 0, wave, lane);
  stage_gemm(A, Bt, &As[1][0], &Bs[1][0], row0, col0, K, 32, wave, lane);

  #pragma unroll 1
  for (int ks = 0; ks < nks; ++ks){
    const int cur = ks & 3;
    if (ks + 2 < nks){
      stage_gemm(A, Bt, &As[(ks + 2) & 3][0], &Bs[(ks + 2) & 3][0],
                 row0, col0, K, (ks + 2) << 5, wave, lane);
      asm volatile("s_waitcnt vmcnt(8)" ::: "memory");
    } else if (ks + 1 < nks){
      asm volatile("s_waitcnt vmcnt(4)" ::: "memory");
    } else {
      asm volatile("s_waitcnt vmcnt(0)" ::: "memory");
    }
    PH_BAR;

    uint4 af[4], bf[4];
    #pragma unroll
    for (int m = 0; m < 4; ++m){
      int rr = wr * 64 + m * 16 + lm;
      af[m] = *(const uint4*)&As[cur][rr * 32 + (l4 ^ (rr & 3)) * 8];
    }
    #pragma unroll
    for (int n = 0; n < 4; ++n){
      int rr = wc * 64 + n * 16 + lm;
      bf[n] = *(const uint4*)&Bs[cur][rr * 32 + (l4 ^ (rr & 3)) * 8];
    }
    __builtin_amdgcn_s_setprio(1);
    #pragma unroll
    for (int m = 0; m < 4; ++m)
      #pragma unroll
      for (int n = 0; n < 4; ++n)
        acc[m][n] = mfma16(af[m], bf[n], acc[m][n]);
    __builtin_amdgcn_s_setprio(0);
    // no trailing barrier: 4-slot ring makes it redundant (see proof above)
  }

  #pragma unroll
  for (int m = 0; m < 4; ++m){
    #pragma unroll
    for (int n = 0; n < 4; ++n){
      int c = col0 + wc * 64 + n * 16 + lm;
      float bv = bias[c];
      #pragma unroll
      for (int r = 0; r < 4; ++r){
        int row = row0 + wr * 64 + m * 16 + l4 * 4 + r;
        float val = acc[m][n][r] + bv;
        if (MODE == 0){
          int h = c / 192, e = c % 192;
          int which = e >> 6, d = e & 63;
          int b = row >> 11, s = row & 2047;
          int bh = b * 16 + h;
          if (which == 2){
            ov[((size_t)bh * HDIM + d) * S_LEN + s] = f2bf(val);
          } else {
            if (which == 0) val *= QSCALE;     // fold softmax scale into Q
            size_t idx = ((size_t)bh * S_LEN + s) * HDIM + d;
            u16* dst = (which == 0) ? oq : ok;
            dst[idx] = f2bf(val);
          }
        } else {
          of[(size_t)row * N + c] = val;
        }
      }
    }
  }
}

// ---- stage (512-thread block): 64x64 K tile + 64x64 V^T tile, swizzled ------
__device__ __forceinline__ void stage_tile8(
    const u16* __restrict__ kB, const u16* __restrict__ vB,
    u16* ldsK, u16* ldsV, int kbase, int wave, int lane)
{
  int ch  = wave * 64 + lane;             // 16B chunk id, 0..511
  int row = ch >> 3;                      // tile row (K: s-row; V: d-row)
  int cc  = (ch & 7) << 4;                // byte col in LDS
  int sc  = cc ^ ((row & 7) << 4);        // byte col in global row (pre-swizzle)
  gload16(kB + (size_t)(kbase + row) * HDIM + (sc >> 1), ldsK + (size_t)wave * 512);
  gload16(vB + (size_t)row * S_LEN + kbase + (sc >> 1), ldsV + (size_t)wave * 512);
}

// ---------------- causal flash attention, 8 waves x 16 q-rows ----------------
// grid 1024: one 128-row strip per block, HEAVY-FIRST (st = 15 - bid>>6).
// __launch_bounds__(512, 6) caps VGPR <= 85 -> 3 blocks/CU (LDS 50KB x 3).
// bh = bid & 63 (XCD-pinned). 2-slot KV ring keeps both barriers (needed).
__global__ __launch_bounds__(512, 6) void k_attn(
    const u16* __restrict__ q, const u16* __restrict__ kk,
    const u16* __restrict__ vt, u16* __restrict__ ctx)
{
  __shared__ u16 KV[2][2][64 * 64];        // [buf][K/V][tile]  32 KB
  __shared__ u16 Ps[8][16][72];            // [wave][q-row][k]  18 KB

  const int bid = blockIdx.x;
  const int bh = bid & 63;
  const int st = 15 - (bid >> 6);          // strip 0..15, heavy first
  const int wave = threadIdx.x >> 6, lane = threadIdx.x & 63;
  const int l4 = lane >> 4, lm = lane & 15;
  const size_t base = (size_t)bh * (S_LEN * HDIM);
  const u16* kB = kk + base;
  const u16* vB = vt + base;               // [d][s]
  const int b = bh >> 4, h = bh & 15;
  const f32x4 fz = {0.f, 0.f, 0.f, 0.f};

  const int q0 = st * 128 + wave * 16;     // this wave's 16 q-rows

  uint4 qf0, qf1;
  {
    const u16* qr = q + base + (size_t)(q0 + lm) * HDIM + l4 * 8;
    qf0 = *(const uint4*)qr;
    qf1 = *(const uint4*)(qr + 32);
  }

  float mr = -1e30f, lsp = 0.f;
  f32x4 acc[4];
  #pragma unroll
  for (int tt = 0; tt < 4; ++tt) acc[tt] = fz;

  const int nkt = 2 * st + 2;

  stage_tile8(kB, vB, &KV[0][0][0], &KV[0][1][0], 0, wave, lane);

  #pragma unroll 1
  for (int kt = 0; kt < nkt; ++kt){
    const int cur = kt & 1;
    const int kbase = kt << 6;
    if (kt + 1 < nkt){
      stage_tile8(kB, vB, &KV[cur ^ 1][0][0], &KV[cur ^ 1][1][0],
                  (kt + 1) << 6, wave, lane);
      asm volatile("s_waitcnt vmcnt(2)" ::: "memory");
    } else {
      asm volatile("s_waitcnt vmcnt(0)" ::: "memory");
    }
    PH_BAR;

    if (kbase < q0 + 16){                  // skip fully-masked tiles (uniform)
      const u16* ldsK = &KV[cur][0][0];
      const u16* ldsV = &KV[cur][1][0];

      // ---- S^T = K Q^T (log2 domain): rows k, cols q ----
      f32x4 sv[4];
      __builtin_amdgcn_s_setprio(1);
      #pragma unroll
      for (int g = 0; g < 4; ++g){
        int rk = g * 16 + lm;
        int xa = (l4 * 16) ^ ((rk & 7) << 4);
        int xb = (64 + l4 * 16) ^ ((rk & 7) << 4);
        const u16* krow = ldsK + rk * 64;
        uint4 kf0 = *(const uint4*)(krow + (xa >> 1));
        uint4 kf1 = *(const uint4*)(krow + (xb >> 1));
        sv[g] = mfma16(kf0, qf0, fz);
        sv[g] = mfma16(kf1, qf1, sv[g]);
      }
      __builtin_amdgcn_s_setprio(0);

      if (kbase + 63 > q0){                // causal tail mask
        #pragma unroll
        for (int g = 0; g < 4; ++g)
          #pragma unroll
          for (int r = 0; r < 4; ++r){
            int kg = kbase + g * 16 + l4 * 4 + r;
            int qg = q0 + lm;
            if (kg > qg) sv[g][r] = -1e30f;
          }
      }

      // lane-local max; __any = cross-lane OR (no shfl on common path)
      float pml = sv[0][0];
      #pragma unroll
      for (int g = 0; g < 4; ++g)
        #pragma unroll
        for (int r = 0; r < 4; ++r) pml = fmaxf(pml, sv[g][r]);

      if (__any(pml > mr + DEFER_THR)){    // rare: exact max + rescale
        float pm = fmaxf(pml, __shfl_xor(pml, 16));
        pm = fmaxf(pm, __shfl_xor(pm, 32));
        float mn = fmaxf(mr, pm);
        float corr = exp2fast(mr - mn);
        mr = mn;
        lsp *= corr;
        float cf[4];
        #pragma unroll
        for (int r = 0; r < 4; ++r) cf[r] = __shfl(corr, l4 * 4 + r);
        #pragma unroll
        for (int tt = 0; tt < 4; ++tt)
          #pragma unroll
          for (int r = 0; r < 4; ++r) acc[tt][r] *= cf[r];
      }

      // P = exp2(S - m); lane-local partial sum; packed b64 writes
      float s_ = 0.f;
      #pragma unroll
      for (int g = 0; g < 4; ++g){
        float p0 = exp2fast(sv[g][0] - mr);
        float p1 = exp2fast(sv[g][1] - mr);
        float p2 = exp2fast(sv[g][2] - mr);
        float p3 = exp2fast(sv[g][3] - mr);
        s_ += (p0 + p1) + (p2 + p3);
        uint2 w;
        w.x = (unsigned)f2bf(p0) | ((unsigned)f2bf(p1) << 16);
        w.y = (unsigned)f2bf(p2) | ((unsigned)f2bf(p3) << 16);
        *(uint2*)&Ps[wave][lm][g * 16 + l4 * 4] = w;
      }
      lsp += s_;

      __builtin_amdgcn_wave_barrier();
      uint4 pa0 = *(const uint4*)&Ps[wave][lm][l4 * 8];
      uint4 pa1 = *(const uint4*)&Ps[wave][lm][32 + l4 * 8];

      // ---- O += P @ V (V^T from LDS, swizzled read) ----
      __builtin_amdgcn_s_setprio(1);
      #pragma unroll
      for (int tt = 0; tt < 4; ++tt){
        int rv = tt * 16 + lm;
        int xa = (l4 * 16) ^ ((rv & 7) << 4);
        int xb = (64 + l4 * 16) ^ ((rv & 7) << 4);
        const u16* vrow = ldsV + rv * 64;
        uint4 v0 = *(const uint4*)(vrow + (xa >> 1));
        uint4 v1 = *(const uint4*)(vrow + (xb >> 1));
        acc[tt] = mfma16(pa0, v0, acc[tt]);
        acc[tt] = mfma16(pa1, v1, acc[tt]);
      }
      __builtin_amdgcn_s_setprio(0);
    }

    PH_BAR;
  }

  // ---- epilogue: reduce deferred sums, normalize, write ----
  lsp += __shfl_xor(lsp, 16);
  lsp += __shfl_xor(lsp, 32);
  float inv_ = 1.0f / lsp;
  float ivr[4];
  #pragma unroll
  for (int r = 0; r < 4; ++r) ivr[r] = __shfl(inv_, l4 * 4 + r);
  #pragma unroll
  for (int tt = 0; tt < 4; ++tt)
    #pragma unroll
    for (int r = 0; r < 4; ++r){
      int srow = q0 + l4 * 4 + r;
      float val = acc[tt][r] * ivr[r];
      ctx[((size_t)b * S_LEN + srow) * HIDDEN + h * HDIM + tt * 16 + lm] = f2bf(val);
    }
}

// ---------------- launch ----------------
extern "C" void kernel_launch(void* const* d_in, const int* in_sizes, int n_in,
                              void* d_out, int out_size, void* d_ws, size_t ws_size,
                              hipStream_t stream)
{
  const float* x     = (const float*)d_in[0];
  // d_in[1] = causal mask (structure known; ignored)
  const float* w_qkv = (const float*)d_in[2];
  const float* b_qkv = (const float*)d_in[3];
  const float* w_out = (const float*)d_in[4];
  const float* b_out = (const float*)d_in[5];

  char* ws = (char*)d_ws;
  u16* xbf   = (u16*)(ws);                 // 16 MB (reused as ctx)
  u16* wqkvT = (u16*)(ws + 16777216);      //  6 MB
  u16* woutT = (u16*)(ws + 23068672);      //  2 MB
  u16* qb    = (u16*)(ws + 25165824);      // 16 MB  (pre-scaled by QSCALE)
  u16* kb    = (u16*)(ws + 41943040);      // 16 MB
  u16* vb    = (u16*)(ws + 58720256);      // 16 MB  V^T: [bh][d][s]

  k_cvt<<<2048, 256, 0, stream>>>(x, xbf, (BATCH * S_LEN * HIDDEN) / 4);
  k_transpose<<<dim3(96, 32), 256, 0, stream>>>(w_qkv, wqkvT, HIDDEN, 3 * HIDDEN);
  k_transpose<<<dim3(32, 32), 256, 0, stream>>>(w_out, woutT, HIDDEN, HIDDEN);
  k_gemm<0><<<24 * 64, 256, 0, stream>>>(xbf, wqkvT, b_qkv,
                                         qb, kb, vb, nullptr,
                                         BATCH * S_LEN, 3 * HIDDEN, HIDDEN, 24);
  k_attn<<<1024, 512, 0, stream>>>(qb, kb, vb, xbf);
  k_gemm<1><<<8 * 64, 256, 0, stream>>>(xbf, woutT, b_out,
                                        nullptr, nullptr, nullptr,
                                        (float*)d_out, BATCH * S_LEN, HIDDEN, HIDDEN, 8);
}

// Round 21
// 190.840 us; speedup vs baseline: 1.0325x; 1.0325x over previous
//
#include <hip/hip_runtime.h>
#include <stdint.h>

#define S_LEN 2048
#define NHEAD 16
#define HDIM  64
#define HIDDEN 1024
#define BATCH 4

typedef float f32x4 __attribute__((ext_vector_type(4)));
typedef __bf16 bf16x8 __attribute__((ext_vector_type(8)));
typedef unsigned short u16;

union U4B8 { uint4 u; bf16x8 b; };

__device__ __forceinline__ bf16x8 as_b8(uint4 u){ U4B8 x; x.u = u; return x.b; }

__device__ __forceinline__ f32x4 mfma16(uint4 a, uint4 b, f32x4 c){
  return __builtin_amdgcn_mfma_f32_16x16x32_bf16(as_b8(a), as_b8(b), c, 0, 0, 0);
}

__device__ __forceinline__ u16 f2bf(float f){
  __bf16 h = (__bf16)f;
  return __builtin_bit_cast(u16, h);
}

__device__ __forceinline__ float exp2fast(float x){
  return __builtin_exp2f(x);            // v_exp_f32 (hardware is base-2)
}

__device__ __forceinline__ void gload16(const void* g, void* l){
  __builtin_amdgcn_global_load_lds(
      (const __attribute__((address_space(1))) unsigned int*)g,
      (__attribute__((address_space(3))) unsigned int*)l, 16, 0, 0);
}

#define QSCALE 0.18033688f   /* 0.125 * log2(e) */
#define DEFER_THR 11.5f      /* = 8 in ln-domain */

#define FENCE asm volatile("" ::: "memory")
#define PH_BAR do{ FENCE; __builtin_amdgcn_s_barrier(); FENCE; }while(0)

// ---------------- convert x: f32 -> bf16 ----------------
__global__ __launch_bounds__(256) void k_cvt(const float* __restrict__ in,
                                             u16* __restrict__ out, int n4){
  int i = blockIdx.x * 256 + threadIdx.x;
  int stride = gridDim.x * 256;
  for (; i < n4; i += stride){
    float4 v = ((const float4*)in)[i];
    unsigned lo = (unsigned)f2bf(v.x) | ((unsigned)f2bf(v.y) << 16);
    unsigned hi = (unsigned)f2bf(v.z) | ((unsigned)f2bf(v.w) << 16);
    ((uint2*)out)[i] = make_uint2(lo, hi);
  }
}

// ---------------- transpose+convert: f32 [K][N] -> bf16 [N][K] ----------------
__global__ __launch_bounds__(256) void k_transpose(const float* __restrict__ in,
                                                   u16* __restrict__ out,
                                                   int K, int N){
  __shared__ float t[32][33];
  int tx = threadIdx.x & 31, ty = threadIdx.x >> 5;
  int n0 = blockIdx.x * 32, k0 = blockIdx.y * 32;
  #pragma unroll
  for (int i = 0; i < 4; ++i)
    t[ty + i*8][tx] = in[(size_t)(k0 + ty + i*8) * N + n0 + tx];
  __syncthreads();
  #pragma unroll
  for (int i = 0; i < 4; ++i)
    out[(size_t)(n0 + ty + i*8) * K + k0 + tx] = f2bf(t[tx][ty + i*8]);
}

// ---- stage one 128x32 A-tile + 128x32 B-tile into LDS (4 loads/thread) ------
__device__ __forceinline__ void stage_gemm(
    const u16* __restrict__ A, const u16* __restrict__ Bt,
    u16* As, u16* Bs, int row0, int col0, int K, int k0, int wave, int lane)
{
  #pragma unroll
  for (int p = 0; p < 2; ++p){
    int chunk = wave * 128 + p * 64 + lane;   // 0..511
    int r = chunk >> 2, cseg = chunk & 3;
    int sseg = cseg ^ (r & 3);                // pre-swizzled source chunk
    const u16* ga = A  + (size_t)(row0 + r) * K + k0 + sseg * 8;
    gload16(ga, As + (size_t)(wave * 128 + p * 64) * 8);
    const u16* gb = Bt + (size_t)(col0 + r) * K + k0 + sseg * 8;
    gload16(gb, Bs + (size_t)(wave * 128 + p * 64) * 8);
  }
}

// ---------------- GEMM: C[M,N] = A[M,K](bf16) @ Bt[N,K](bf16)^T + bias -------
// 128x128 tile, 4 waves, BK=32. TRIPLE-buffered LDS, depth-2 prefetch,
// counted vmcnt(8), raw s_barrier pair, T1 XCD row-band grid swizzle.
// MODE 0: scatter q (pre-scaled) / k into [B*H][S][D], V^T into [B*H][D][S].
// MODE 1: f32 out [M,N].
template<int MODE>
__global__ __launch_bounds__(256) void k_gemm(
    const u16* __restrict__ A, const u16* __restrict__ Bt,
    const float* __restrict__ bias,
    u16* __restrict__ oq, u16* __restrict__ ok, u16* __restrict__ ov,
    float* __restrict__ of, int M, int N, int K, int nx)
{
  __shared__ u16 As[3][128 * 32];   // 24 KB
  __shared__ u16 Bs[3][128 * 32];   // 24 KB
  const int tid  = threadIdx.x;
  const int wave = tid >> 6, lane = tid & 63;
  const int l4 = lane >> 4, lm = lane & 15;
  const int wr = wave >> 1, wc = wave & 1;

  // XCD row-band swizzle: xcd gets rows [xcd*ny/8, ...), all cols.
  const int bid = blockIdx.x;
  const int nwg = gridDim.x;
  const int ny8 = nwg / (8 * nx);           // row-panels per XCD
  const int xcd = bid & 7, t = bid >> 3;
  const int by = xcd * ny8 + t / nx;
  const int bx = t % nx;
  const int row0 = by * 128;
  const int col0 = bx * 128;

  const f32x4 fzero = {0.f, 0.f, 0.f, 0.f};
  f32x4 acc[4][4];
  #pragma unroll
  for (int m = 0; m < 4; ++m)
    #pragma unroll
    for (int n = 0; n < 4; ++n) acc[m][n] = fzero;

  const int nks = K >> 5;
  stage_gemm(A, Bt, &As[0][0], &Bs[0][0], row0, col0, K, 0, wave, lane);
  stage_gemm(A, Bt, &As[1][0], &Bs[1][0], row0, col0, K, 32, wave, lane);

  int cur = 0;
  #pragma unroll 1
  for (int ks = 0; ks < nks; ++ks){
    if (ks + 2 < nks){
      int nxt = cur + 2; if (nxt >= 3) nxt -= 3;
      stage_gemm(A, Bt, &As[nxt][0], &Bs[nxt][0],
                 row0, col0, K, (ks + 2) << 5, wave, lane);
      asm volatile("s_waitcnt vmcnt(8)" ::: "memory");
    } else if (ks + 1 < nks){
      asm volatile("s_waitcnt vmcnt(4)" ::: "memory");
    } else {
      asm volatile("s_waitcnt vmcnt(0)" ::: "memory");
    }
    PH_BAR;

    uint4 af[4], bf[4];
    #pragma unroll
    for (int m = 0; m < 4; ++m){
      int rr = wr * 64 + m * 16 + lm;
      af[m] = *(const uint4*)&As[cur][rr * 32 + (l4 ^ (rr & 3)) * 8];
    }
    #pragma unroll
    for (int n = 0; n < 4; ++n){
      int rr = wc * 64 + n * 16 + lm;
      bf[n] = *(const uint4*)&Bs[cur][rr * 32 + (l4 ^ (rr & 3)) * 8];
    }
    __builtin_amdgcn_s_setprio(1);
    #pragma unroll
    for (int m = 0; m < 4; ++m)
      #pragma unroll
      for (int n = 0; n < 4; ++n)
        acc[m][n] = mfma16(af[m], bf[n], acc[m][n]);
    __builtin_amdgcn_s_setprio(0);

    PH_BAR;

    cur = cur + 1; if (cur >= 3) cur -= 3;
  }

  #pragma unroll
  for (int m = 0; m < 4; ++m){
    #pragma unroll
    for (int n = 0; n < 4; ++n){
      int c = col0 + wc * 64 + n * 16 + lm;
      float bv = bias[c];
      #pragma unroll
      for (int r = 0; r < 4; ++r){
        int row = row0 + wr * 64 + m * 16 + l4 * 4 + r;
        float val = acc[m][n][r] + bv;
        if (MODE == 0){
          int h = c / 192, e = c % 192;
          int which = e >> 6, d = e & 63;
          int b = row >> 11, s = row & 2047;
          int bh = b * 16 + h;
          if (which == 2){
            ov[((size_t)bh * HDIM + d) * S_LEN + s] = f2bf(val);
          } else {
            if (which == 0) val *= QSCALE;     // fold softmax scale into Q
            size_t idx = ((size_t)bh * S_LEN + s) * HDIM + d;
            u16* dst = (which == 0) ? oq : ok;
            dst[idx] = f2bf(val);
          }
        } else {
          of[(size_t)row * N + c] = val;
        }
      }
    }
  }
}

// ---- stage (512-thread block): 64x64 K tile + 64x64 V^T tile, swizzled ------
__device__ __forceinline__ void stage_tile8(
    const u16* __restrict__ kB, const u16* __restrict__ vB,
    u16* ldsK, u16* ldsV, int kbase, int wave, int lane)
{
  int ch  = wave * 64 + lane;             // 16B chunk id, 0..511
  int row = ch >> 3;                      // tile row (K: s-row; V: d-row)
  int cc  = (ch & 7) << 4;                // byte col in LDS
  int sc  = cc ^ ((row & 7) << 4);        // byte col in global row (pre-swizzle)
  gload16(kB + (size_t)(kbase + row) * HDIM + (sc >> 1), ldsK + (size_t)wave * 512);
  gload16(vB + (size_t)row * S_LEN + kbase + (sc >> 1), ldsV + (size_t)wave * 512);
}

// ---------------- causal flash attention, 8 waves x 16 q-rows ----------------
// grid 1024: one 128-row strip per block, HEAVY-FIRST (st = 15 - bid>>6).
// __launch_bounds__(512, 6) caps VGPR <= 85 -> 3 blocks/CU (LDS 50KB x 3).
// bh = bid & 63 (XCD-pinned). 2-slot KV ring with both barriers.
__global__ __launch_bounds__(512, 6) void k_attn(
    const u16* __restrict__ q, const u16* __restrict__ kk,
    const u16* __restrict__ vt, u16* __restrict__ ctx)
{
  __shared__ u16 KV[2][2][64 * 64];        // [buf][K/V][tile]  32 KB
  __shared__ u16 Ps[8][16][72];            // [wave][q-row][k]  18 KB

  const int bid = blockIdx.x;
  const int bh = bid & 63;
  const int st = 15 - (bid >> 6);          // strip 0..15, heavy first
  const int wave = threadIdx.x >> 6, lane = threadIdx.x & 63;
  const int l4 = lane >> 4, lm = lane & 15;
  const size_t base = (size_t)bh * (S_LEN * HDIM);
  const u16* kB = kk + base;
  const u16* vB = vt + base;               // [d][s]
  const int b = bh >> 4, h = bh & 15;
  const f32x4 fz = {0.f, 0.f, 0.f, 0.f};

  const int q0 = st * 128 + wave * 16;     // this wave's 16 q-rows

  uint4 qf0, qf1;
  {
    const u16* qr = q + base + (size_t)(q0 + lm) * HDIM + l4 * 8;
    qf0 = *(const uint4*)qr;
    qf1 = *(const uint4*)(qr + 32);
  }

  float mr = -1e30f, lsp = 0.f;
  f32x4 acc[4];
  #pragma unroll
  for (int tt = 0; tt < 4; ++tt) acc[tt] = fz;

  const int nkt = 2 * st + 2;

  stage_tile8(kB, vB, &KV[0][0][0], &KV[0][1][0], 0, wave, lane);

  #pragma unroll 1
  for (int kt = 0; kt < nkt; ++kt){
    const int cur = kt & 1;
    const int kbase = kt << 6;
    if (kt + 1 < nkt){
      stage_tile8(kB, vB, &KV[cur ^ 1][0][0], &KV[cur ^ 1][1][0],
                  (kt + 1) << 6, wave, lane);
      asm volatile("s_waitcnt vmcnt(2)" ::: "memory");
    } else {
      asm volatile("s_waitcnt vmcnt(0)" ::: "memory");
    }
    PH_BAR;

    if (kbase < q0 + 16){                  // skip fully-masked tiles (uniform)
      const u16* ldsK = &KV[cur][0][0];
      const u16* ldsV = &KV[cur][1][0];

      // ---- S^T = K Q^T (log2 domain): rows k, cols q ----
      f32x4 sv[4];
      __builtin_amdgcn_s_setprio(1);
      #pragma unroll
      for (int g = 0; g < 4; ++g){
        int rk = g * 16 + lm;
        int xa = (l4 * 16) ^ ((rk & 7) << 4);
        int xb = (64 + l4 * 16) ^ ((rk & 7) << 4);
        const u16* krow = ldsK + rk * 64;
        uint4 kf0 = *(const uint4*)(krow + (xa >> 1));
        uint4 kf1 = *(const uint4*)(krow + (xb >> 1));
        sv[g] = mfma16(kf0, qf0, fz);
        sv[g] = mfma16(kf1, qf1, sv[g]);
      }
      __builtin_amdgcn_s_setprio(0);

      if (kbase + 63 > q0){                // causal tail mask
        #pragma unroll
        for (int g = 0; g < 4; ++g)
          #pragma unroll
          for (int r = 0; r < 4; ++r){
            int kg = kbase + g * 16 + l4 * 4 + r;
            int qg = q0 + lm;
            if (kg > qg) sv[g][r] = -1e30f;
          }
      }

      // lane-local max; __any = cross-lane OR (no shfl on common path)
      float pml = sv[0][0];
      #pragma unroll
      for (int g = 0; g < 4; ++g)
        #pragma unroll
        for (int r = 0; r < 4; ++r) pml = fmaxf(pml, sv[g][r]);

      if (__any(pml > mr + DEFER_THR)){    // rare: exact max + rescale
        float pm = fmaxf(pml, __shfl_xor(pml, 16));
        pm = fmaxf(pm, __shfl_xor(pm, 32));
        float mn = fmaxf(mr, pm);
        float corr = exp2fast(mr - mn);
        mr = mn;
        lsp *= corr;
        float cf[4];
        #pragma unroll
        for (int r = 0; r < 4; ++r) cf[r] = __shfl(corr, l4 * 4 + r);
        #pragma unroll
        for (int tt = 0; tt < 4; ++tt)
          #pragma unroll
          for (int r = 0; r < 4; ++r) acc[tt][r] *= cf[r];
      }

      // P = exp2(S - m); lane-local partial sum; packed b64 writes
      float s_ = 0.f;
      #pragma unroll
      for (int g = 0; g < 4; ++g){
        float p0 = exp2fast(sv[g][0] - mr);
        float p1 = exp2fast(sv[g][1] - mr);
        float p2 = exp2fast(sv[g][2] - mr);
        float p3 = exp2fast(sv[g][3] - mr);
        s_ += (p0 + p1) + (p2 + p3);
        uint2 w;
        w.x = (unsigned)f2bf(p0) | ((unsigned)f2bf(p1) << 16);
        w.y = (unsigned)f2bf(p2) | ((unsigned)f2bf(p3) << 16);
        *(uint2*)&Ps[wave][lm][g * 16 + l4 * 4] = w;
      }
      lsp += s_;

      __builtin_amdgcn_wave_barrier();
      uint4 pa0 = *(const uint4*)&Ps[wave][lm][l4 * 8];
      uint4 pa1 = *(const uint4*)&Ps[wave][lm][32 + l4 * 8];

      // ---- O += P @ V (V^T from LDS, swizzled read) ----
      __builtin_amdgcn_s_setprio(1);
      #pragma unroll
      for (int tt = 0; tt < 4; ++tt){
        int rv = tt * 16 + lm;
        int xa = (l4 * 16) ^ ((rv & 7) << 4);
        int xb = (64 + l4 * 16) ^ ((rv & 7) << 4);
        const u16* vrow = ldsV + rv * 64;
        uint4 v0 = *(const uint4*)(vrow + (xa >> 1));
        uint4 v1 = *(const uint4*)(vrow + (xb >> 1));
        acc[tt] = mfma16(pa0, v0, acc[tt]);
        acc[tt] = mfma16(pa1, v1, acc[tt]);
      }
      __builtin_amdgcn_s_setprio(0);
    }

    PH_BAR;
  }

  // ---- epilogue: reduce deferred sums, normalize, write ----
  lsp += __shfl_xor(lsp, 16);
  lsp += __shfl_xor(lsp, 32);
  float inv_ = 1.0f / lsp;
  float ivr[4];
  #pragma unroll
  for (int r = 0; r < 4; ++r) ivr[r] = __shfl(inv_, l4 * 4 + r);
  #pragma unroll
  for (int tt = 0; tt < 4; ++tt)
    #pragma unroll
    for (int r = 0; r < 4; ++r){
      int srow = q0 + l4 * 4 + r;
      float val = acc[tt][r] * ivr[r];
      ctx[((size_t)b * S_LEN + srow) * HIDDEN + h * HDIM + tt * 16 + lm] = f2bf(val);
    }
}

// ---------------- launch ----------------
extern "C" void kernel_launch(void* const* d_in, const int* in_sizes, int n_in,
                              void* d_out, int out_size, void* d_ws, size_t ws_size,
                              hipStream_t stream)
{
  const float* x     = (const float*)d_in[0];
  // d_in[1] = causal mask (structure known; ignored)
  const float* w_qkv = (const float*)d_in[2];
  const float* b_qkv = (const float*)d_in[3];
  const float* w_out = (const float*)d_in[4];
  const float* b_out = (const float*)d_in[5];

  char* ws = (char*)d_ws;
  u16* xbf   = (u16*)(ws);                 // 16 MB (reused as ctx)
  u16* wqkvT = (u16*)(ws + 16777216);      //  6 MB
  u16* woutT = (u16*)(ws + 23068672);      //  2 MB
  u16* qb    = (u16*)(ws + 25165824);      // 16 MB  (pre-scaled by QSCALE)
  u16* kb    = (u16*)(ws + 41943040);      // 16 MB
  u16* vb    = (u16*)(ws + 58720256);      // 16 MB  V^T: [bh][d][s]

  k_cvt<<<2048, 256, 0, stream>>>(x, xbf, (BATCH * S_LEN * HIDDEN) / 4);
  k_transpose<<<dim3(96, 32), 256, 0, stream>>>(w_qkv, wqkvT, HIDDEN, 3 * HIDDEN);
  k_transpose<<<dim3(32, 32), 256, 0, stream>>>(w_out, woutT, HIDDEN, HIDDEN);
  k_gemm<0><<<24 * 64, 256, 0, stream>>>(xbf, wqkvT, b_qkv,
                                         qb, kb, vb, nullptr,
                                         BATCH * S_LEN, 3 * HIDDEN, HIDDEN, 24);
  k_attn<<<1024, 512, 0, stream>>>(qb, kb, vb, xbf);
  k_gemm<1><<<8 * 64, 256, 0, stream>>>(xbf, woutT, b_out,
                                        nullptr, nullptr, nullptr,
                                        (float*)d_out, BATCH * S_LEN, HIDDEN, HIDDEN, 8);
}

// Round 22
// 187.612 us; speedup vs baseline: 1.0503x; 1.0172x over previous
//
#include <hip/hip_runtime.h>
#include <stdint.h>

#define S_LEN 2048
#define NHEAD 16
#define HDIM  64
#define HIDDEN 1024
#define BATCH 4

typedef float f32x4 __attribute__((ext_vector_type(4)));
typedef __bf16 bf16x8 __attribute__((ext_vector_type(8)));
typedef unsigned short u16;

union U4B8 { uint4 u; bf16x8 b; };

__device__ __forceinline__ bf16x8 as_b8(uint4 u){ U4B8 x; x.u = u; return x.b; }

__device__ __forceinline__ f32x4 mfma16(uint4 a, uint4 b, f32x4 c){
  return __builtin_amdgcn_mfma_f32_16x16x32_bf16(as_b8(a), as_b8(b), c, 0, 0, 0);
}

__device__ __forceinline__ u16 f2bf(float f){
  __bf16 h = (__bf16)f;
  return __builtin_bit_cast(u16, h);
}

__device__ __forceinline__ float exp2fast(float x){
  return __builtin_exp2f(x);            // v_exp_f32 (hardware is base-2)
}

__device__ __forceinline__ void gload16(const void* g, void* l){
  __builtin_amdgcn_global_load_lds(
      (const __attribute__((address_space(1))) unsigned int*)g,
      (__attribute__((address_space(3))) unsigned int*)l, 16, 0, 0);
}

#define QSCALE 0.18033688f   /* 0.125 * log2(e) */
#define DEFER_THR 11.5f      /* = 8 in ln-domain */

#define FENCE asm volatile("" ::: "memory")
#define PH_BAR do{ FENCE; __builtin_amdgcn_s_barrier(); FENCE; }while(0)

// ---------- fused prologue: x cvt + both weight transposes (independent) -----
// bid in [0,2048): cvt x f32->bf16 (grid-stride over 2M float4 groups)
// bid in [2048,5120): transpose+cvt w_qkv f32 [1024][3072] -> bf16 [3072][1024]
// bid in [5120,6144): transpose+cvt w_out f32 [1024][1024] -> bf16 [1024][1024]
__global__ __launch_bounds__(256) void k_prep(
    const float* __restrict__ x,     u16* __restrict__ xbf,
    const float* __restrict__ wqkv,  u16* __restrict__ wqkvT,
    const float* __restrict__ wout,  u16* __restrict__ woutT)
{
  __shared__ float t[32][33];
  const int bid = blockIdx.x;

  if (bid < 2048){
    const int n4 = (BATCH * S_LEN * HIDDEN) / 4;
    int i = bid * 256 + threadIdx.x;
    const int stride = 2048 * 256;
    for (; i < n4; i += stride){
      float4 v = ((const float4*)x)[i];
      unsigned lo = (unsigned)f2bf(v.x) | ((unsigned)f2bf(v.y) << 16);
      unsigned hi = (unsigned)f2bf(v.z) | ((unsigned)f2bf(v.w) << 16);
      ((uint2*)xbf)[i] = make_uint2(lo, hi);
    }
    return;
  }

  const float* in; u16* out; int K, N, n0, k0;
  if (bid < 5120){
    int tt = bid - 2048;                 // 96 x 32 tiles
    in = wqkv; out = wqkvT; K = HIDDEN; N = 3 * HIDDEN;
    n0 = (tt % 96) * 32; k0 = (tt / 96) * 32;
  } else {
    int tt = bid - 5120;                 // 32 x 32 tiles
    in = wout; out = woutT; K = HIDDEN; N = HIDDEN;
    n0 = (tt % 32) * 32; k0 = (tt / 32) * 32;
  }
  int tx = threadIdx.x & 31, ty = threadIdx.x >> 5;
  #pragma unroll
  for (int i = 0; i < 4; ++i)
    t[ty + i*8][tx] = in[(size_t)(k0 + ty + i*8) * N + n0 + tx];
  __syncthreads();
  #pragma unroll
  for (int i = 0; i < 4; ++i)
    out[(size_t)(n0 + ty + i*8) * K + k0 + tx] = f2bf(t[tx][ty + i*8]);
}

// ---- stage one 128x32 A-tile + 128x32 B-tile into LDS (4 loads/thread) ------
__device__ __forceinline__ void stage_gemm(
    const u16* __restrict__ A, const u16* __restrict__ Bt,
    u16* As, u16* Bs, int row0, int col0, int K, int k0, int wave, int lane)
{
  #pragma unroll
  for (int p = 0; p < 2; ++p){
    int chunk = wave * 128 + p * 64 + lane;   // 0..511
    int r = chunk >> 2, cseg = chunk & 3;
    int sseg = cseg ^ (r & 3);                // pre-swizzled source chunk
    const u16* ga = A  + (size_t)(row0 + r) * K + k0 + sseg * 8;
    gload16(ga, As + (size_t)(wave * 128 + p * 64) * 8);
    const u16* gb = Bt + (size_t)(col0 + r) * K + k0 + sseg * 8;
    gload16(gb, Bs + (size_t)(wave * 128 + p * 64) * 8);
  }
}

// ---------------- GEMM: C[M,N] = A[M,K](bf16) @ Bt[N,K](bf16)^T + bias -------
// 128x128 tile, 4 waves, BK=32. TRIPLE-buffered LDS, depth-2 prefetch,
// counted vmcnt(8), raw s_barrier pair, T1 XCD row-band grid swizzle.
// MODE 0: scatter q (pre-scaled) / k into [B*H][S][D], V^T into [B*H][D][S].
// MODE 1: f32 out [M,N].
template<int MODE>
__global__ __launch_bounds__(256) void k_gemm(
    const u16* __restrict__ A, const u16* __restrict__ Bt,
    const float* __restrict__ bias,
    u16* __restrict__ oq, u16* __restrict__ ok, u16* __restrict__ ov,
    float* __restrict__ of, int M, int N, int K, int nx)
{
  __shared__ u16 As[3][128 * 32];   // 24 KB
  __shared__ u16 Bs[3][128 * 32];   // 24 KB
  const int tid  = threadIdx.x;
  const int wave = tid >> 6, lane = tid & 63;
  const int l4 = lane >> 4, lm = lane & 15;
  const int wr = wave >> 1, wc = wave & 1;

  // XCD row-band swizzle: xcd gets rows [xcd*ny/8, ...), all cols.
  const int bid = blockIdx.x;
  const int nwg = gridDim.x;
  const int ny8 = nwg / (8 * nx);           // row-panels per XCD
  const int xcd = bid & 7, t = bid >> 3;
  const int by = xcd * ny8 + t / nx;
  const int bx = t % nx;
  const int row0 = by * 128;
  const int col0 = bx * 128;

  const f32x4 fzero = {0.f, 0.f, 0.f, 0.f};
  f32x4 acc[4][4];
  #pragma unroll
  for (int m = 0; m < 4; ++m)
    #pragma unroll
    for (int n = 0; n < 4; ++n) acc[m][n] = fzero;

  const int nks = K >> 5;
  stage_gemm(A, Bt, &As[0][0], &Bs[0][0], row0, col0, K, 0, wave, lane);
  stage_gemm(A, Bt, &As[1][0], &Bs[1][0], row0, col0, K, 32, wave, lane);

  int cur = 0;
  #pragma unroll 1
  for (int ks = 0; ks < nks; ++ks){
    if (ks + 2 < nks){
      int nxt = cur + 2; if (nxt >= 3) nxt -= 3;
      stage_gemm(A, Bt, &As[nxt][0], &Bs[nxt][0],
                 row0, col0, K, (ks + 2) << 5, wave, lane);
      asm volatile("s_waitcnt vmcnt(8)" ::: "memory");
    } else if (ks + 1 < nks){
      asm volatile("s_waitcnt vmcnt(4)" ::: "memory");
    } else {
      asm volatile("s_waitcnt vmcnt(0)" ::: "memory");
    }
    PH_BAR;

    uint4 af[4], bf[4];
    #pragma unroll
    for (int m = 0; m < 4; ++m){
      int rr = wr * 64 + m * 16 + lm;
      af[m] = *(const uint4*)&As[cur][rr * 32 + (l4 ^ (rr & 3)) * 8];
    }
    #pragma unroll
    for (int n = 0; n < 4; ++n){
      int rr = wc * 64 + n * 16 + lm;
      bf[n] = *(const uint4*)&Bs[cur][rr * 32 + (l4 ^ (rr & 3)) * 8];
    }
    __builtin_amdgcn_s_setprio(1);
    #pragma unroll
    for (int m = 0; m < 4; ++m)
      #pragma unroll
      for (int n = 0; n < 4; ++n)
        acc[m][n] = mfma16(af[m], bf[n], acc[m][n]);
    __builtin_amdgcn_s_setprio(0);

    PH_BAR;

    cur = cur + 1; if (cur >= 3) cur -= 3;
  }

  #pragma unroll
  for (int m = 0; m < 4; ++m){
    #pragma unroll
    for (int n = 0; n < 4; ++n){
      int c = col0 + wc * 64 + n * 16 + lm;
      float bv = bias[c];
      #pragma unroll
      for (int r = 0; r < 4; ++r){
        int row = row0 + wr * 64 + m * 16 + l4 * 4 + r;
        float val = acc[m][n][r] + bv;
        if (MODE == 0){
          int h = c / 192, e = c % 192;
          int which = e >> 6, d = e & 63;
          int b = row >> 11, s = row & 2047;
          int bh = b * 16 + h;
          if (which == 2){
            ov[((size_t)bh * HDIM + d) * S_LEN + s] = f2bf(val);
          } else {
            if (which == 0) val *= QSCALE;     // fold softmax scale into Q
            size_t idx = ((size_t)bh * S_LEN + s) * HDIM + d;
            u16* dst = (which == 0) ? oq : ok;
            dst[idx] = f2bf(val);
          }
        } else {
          of[(size_t)row * N + c] = val;
        }
      }
    }
  }
}

// ---- stage (512-thread block): 64x64 K tile + 64x64 V^T tile, swizzled ------
__device__ __forceinline__ void stage_tile8(
    const u16* __restrict__ kB, const u16* __restrict__ vB,
    u16* ldsK, u16* ldsV, int kbase, int wave, int lane)
{
  int ch  = wave * 64 + lane;             // 16B chunk id, 0..511
  int row = ch >> 3;                      // tile row (K: s-row; V: d-row)
  int cc  = (ch & 7) << 4;                // byte col in LDS
  int sc  = cc ^ ((row & 7) << 4);        // byte col in global row (pre-swizzle)
  gload16(kB + (size_t)(kbase + row) * HDIM + (sc >> 1), ldsK + (size_t)wave * 512);
  gload16(vB + (size_t)row * S_LEN + kbase + (sc >> 1), ldsV + (size_t)wave * 512);
}

// ---------------- causal flash attention, 8 waves x 16 q-rows ----------------
// grid 1024: one 128-row strip per block, HEAVY-FIRST (st = 15 - bid>>6).
// __launch_bounds__(512, 6) caps VGPR <= 85 -> 3 blocks/CU (LDS 50KB x 3).
// bh = bid & 63 (XCD-pinned). 2-slot KV ring with both barriers.
__global__ __launch_bounds__(512, 6) void k_attn(
    const u16* __restrict__ q, const u16* __restrict__ kk,
    const u16* __restrict__ vt, u16* __restrict__ ctx)
{
  __shared__ u16 KV[2][2][64 * 64];        // [buf][K/V][tile]  32 KB
  __shared__ u16 Ps[8][16][72];            // [wave][q-row][k]  18 KB

  const int bid = blockIdx.x;
  const int bh = bid & 63;
  const int st = 15 - (bid >> 6);          // strip 0..15, heavy first
  const int wave = threadIdx.x >> 6, lane = threadIdx.x & 63;
  const int l4 = lane >> 4, lm = lane & 15;
  const size_t base = (size_t)bh * (S_LEN * HDIM);
  const u16* kB = kk + base;
  const u16* vB = vt + base;               // [d][s]
  const int b = bh >> 4, h = bh & 15;
  const f32x4 fz = {0.f, 0.f, 0.f, 0.f};

  const int q0 = st * 128 + wave * 16;     // this wave's 16 q-rows

  uint4 qf0, qf1;
  {
    const u16* qr = q + base + (size_t)(q0 + lm) * HDIM + l4 * 8;
    qf0 = *(const uint4*)qr;
    qf1 = *(const uint4*)(qr + 32);
  }

  float mr = -1e30f, lsp = 0.f;
  f32x4 acc[4];
  #pragma unroll
  for (int tt = 0; tt < 4; ++tt) acc[tt] = fz;

  const int nkt = 2 * st + 2;

  stage_tile8(kB, vB, &KV[0][0][0], &KV[0][1][0], 0, wave, lane);

  #pragma unroll 1
  for (int kt = 0; kt < nkt; ++kt){
    const int cur = kt & 1;
    const int kbase = kt << 6;
    if (kt + 1 < nkt){
      stage_tile8(kB, vB, &KV[cur ^ 1][0][0], &KV[cur ^ 1][1][0],
                  (kt + 1) << 6, wave, lane);
      asm volatile("s_waitcnt vmcnt(2)" ::: "memory");
    } else {
      asm volatile("s_waitcnt vmcnt(0)" ::: "memory");
    }
    PH_BAR;

    if (kbase < q0 + 16){                  // skip fully-masked tiles (uniform)
      const u16* ldsK = &KV[cur][0][0];
      const u16* ldsV = &KV[cur][1][0];

      // ---- S^T = K Q^T (log2 domain): rows k, cols q ----
      f32x4 sv[4];
      __builtin_amdgcn_s_setprio(1);
      #pragma unroll
      for (int g = 0; g < 4; ++g){
        int rk = g * 16 + lm;
        int xa = (l4 * 16) ^ ((rk & 7) << 4);
        int xb = (64 + l4 * 16) ^ ((rk & 7) << 4);
        const u16* krow = ldsK + rk * 64;
        uint4 kf0 = *(const uint4*)(krow + (xa >> 1));
        uint4 kf1 = *(const uint4*)(krow + (xb >> 1));
        sv[g] = mfma16(kf0, qf0, fz);
        sv[g] = mfma16(kf1, qf1, sv[g]);
      }
      __builtin_amdgcn_s_setprio(0);

      if (kbase + 63 > q0){                // causal tail mask
        #pragma unroll
        for (int g = 0; g < 4; ++g)
          #pragma unroll
          for (int r = 0; r < 4; ++r){
            int kg = kbase + g * 16 + l4 * 4 + r;
            int qg = q0 + lm;
            if (kg > qg) sv[g][r] = -1e30f;
          }
      }

      // lane-local max; __any = cross-lane OR (no shfl on common path)
      float pml = sv[0][0];
      #pragma unroll
      for (int g = 0; g < 4; ++g)
        #pragma unroll
        for (int r = 0; r < 4; ++r) pml = fmaxf(pml, sv[g][r]);

      if (__any(pml > mr + DEFER_THR)){    // rare: exact max + rescale
        float pm = fmaxf(pml, __shfl_xor(pml, 16));
        pm = fmaxf(pm, __shfl_xor(pm, 32));
        float mn = fmaxf(mr, pm);
        float corr = exp2fast(mr - mn);
        mr = mn;
        lsp *= corr;
        float cf[4];
        #pragma unroll
        for (int r = 0; r < 4; ++r) cf[r] = __shfl(corr, l4 * 4 + r);
        #pragma unroll
        for (int tt = 0; tt < 4; ++tt)
          #pragma unroll
          for (int r = 0; r < 4; ++r) acc[tt][r] *= cf[r];
      }

      // P = exp2(S - m); lane-local partial sum; packed b64 writes
      float s_ = 0.f;
      #pragma unroll
      for (int g = 0; g < 4; ++g){
        float p0 = exp2fast(sv[g][0] - mr);
        float p1 = exp2fast(sv[g][1] - mr);
        float p2 = exp2fast(sv[g][2] - mr);
        float p3 = exp2fast(sv[g][3] - mr);
        s_ += (p0 + p1) + (p2 + p3);
        uint2 w;
        w.x = (unsigned)f2bf(p0) | ((unsigned)f2bf(p1) << 16);
        w.y = (unsigned)f2bf(p2) | ((unsigned)f2bf(p3) << 16);
        *(uint2*)&Ps[wave][lm][g * 16 + l4 * 4] = w;
      }
      lsp += s_;

      __builtin_amdgcn_wave_barrier();
      uint4 pa0 = *(const uint4*)&Ps[wave][lm][l4 * 8];
      uint4 pa1 = *(const uint4*)&Ps[wave][lm][32 + l4 * 8];

      // ---- O += P @ V (V^T from LDS, swizzled read) ----
      __builtin_amdgcn_s_setprio(1);
      #pragma unroll
      for (int tt = 0; tt < 4; ++tt){
        int rv = tt * 16 + lm;
        int xa = (l4 * 16) ^ ((rv & 7) << 4);
        int xb = (64 + l4 * 16) ^ ((rv & 7) << 4);
        const u16* vrow = ldsV + rv * 64;
        uint4 v0 = *(const uint4*)(vrow + (xa >> 1));
        uint4 v1 = *(const uint4*)(vrow + (xb >> 1));
        acc[tt] = mfma16(pa0, v0, acc[tt]);
        acc[tt] = mfma16(pa1, v1, acc[tt]);
      }
      __builtin_amdgcn_s_setprio(0);
    }

    PH_BAR;
  }

  // ---- epilogue: reduce deferred sums, normalize, write ----
  lsp += __shfl_xor(lsp, 16);
  lsp += __shfl_xor(lsp, 32);
  float inv_ = 1.0f / lsp;
  float ivr[4];
  #pragma unroll
  for (int r = 0; r < 4; ++r) ivr[r] = __shfl(inv_, l4 * 4 + r);
  #pragma unroll
  for (int tt = 0; tt < 4; ++tt)
    #pragma unroll
    for (int r = 0; r < 4; ++r){
      int srow = q0 + l4 * 4 + r;
      float val = acc[tt][r] * ivr[r];
      ctx[((size_t)b * S_LEN + srow) * HIDDEN + h * HDIM + tt * 16 + lm] = f2bf(val);
    }
}

// ---------------- launch ----------------
extern "C" void kernel_launch(void* const* d_in, const int* in_sizes, int n_in,
                              void* d_out, int out_size, void* d_ws, size_t ws_size,
                              hipStream_t stream)
{
  const float* x     = (const float*)d_in[0];
  // d_in[1] = causal mask (structure known; ignored)
  const float* w_qkv = (const float*)d_in[2];
  const float* b_qkv = (const float*)d_in[3];
  const float* w_out = (const float*)d_in[4];
  const float* b_out = (const float*)d_in[5];

  char* ws = (char*)d_ws;
  u16* xbf   = (u16*)(ws);                 // 16 MB (reused as ctx)
  u16* wqkvT = (u16*)(ws + 16777216);      //  6 MB
  u16* woutT = (u16*)(ws + 23068672);      //  2 MB
  u16* qb    = (u16*)(ws + 25165824);      // 16 MB  (pre-scaled by QSCALE)
  u16* kb    = (u16*)(ws + 41943040);      // 16 MB
  u16* vb    = (u16*)(ws + 58720256);      // 16 MB  V^T: [bh][d][s]

  k_prep<<<6144, 256, 0, stream>>>(x, xbf, w_qkv, wqkvT, w_out, woutT);
  k_gemm<0><<<24 * 64, 256, 0, stream>>>(xbf, wqkvT, b_qkv,
                                         qb, kb, vb, nullptr,
                                         BATCH * S_LEN, 3 * HIDDEN, HIDDEN, 24);
  k_attn<<<1024, 512, 0, stream>>>(qb, kb, vb, xbf);
  k_gemm<1><<<8 * 64, 256, 0, stream>>>(xbf, woutT, b_out,
                                        nullptr, nullptr, nullptr,
                                        (float*)d_out, BATCH * S_LEN, HIDDEN, HIDDEN, 8);
}